// Round 6
// baseline (1698.979 us; speedup 1.0000x reference)
//
#include <hip/hip_runtime.h>
#include <stdint.h>

typedef unsigned short u16;
typedef short v8s __attribute__((ext_vector_type(8)));
typedef float v4f __attribute__((ext_vector_type(4)));
typedef uint32_t v2u __attribute__((ext_vector_type(2)));

#define DIM 192
#define NH 6
#define NTOK 64
#define IMG 224
#define NWIN 28
#define NB 8
#define SCALE 0.17677669529663687f
#define WPB 4                 // windows per block
#define NGRP (NWIN*NWIN/WPB)  // 196 window-groups per image
#define AO_STR 200            // bf16 stride for attn_out tile

__device__ __forceinline__ u16 f2bf(float f) {
    union { float f; uint32_t u; } v; v.f = f;
    return (u16)((v.u + 0x7FFFu + ((v.u >> 16) & 1u)) >> 16);
}
__device__ __forceinline__ uint32_t pk2(float lo, float hi) {
    return (uint32_t)f2bf(lo) | ((uint32_t)f2bf(hi) << 16);
}

// ---- prep: bf16 weights (SCALE folded into q rows), scaled bias, expanded bias table ----
__global__ void prep_kernel(const float* __restrict__ qkv_w,
                            const float* __restrict__ qkv_b,
                            const float* __restrict__ proj_w,
                            const float* __restrict__ rel_bias,
                            const int* __restrict__ rel_idx,
                            u16* __restrict__ qw, u16* __restrict__ pw,
                            float* __restrict__ qb2, float* __restrict__ biasT) {
    int i = blockIdx.x * 256 + threadIdx.x;
    if (i < 3*DIM*DIM) {
        float s = (i < DIM*DIM) ? SCALE : 1.f;
        qw[i] = f2bf(qkv_w[i] * s);
    }
    if (i < DIM*DIM) pw[i] = f2bf(proj_w[i]);
    if (i < 3*DIM)   qb2[i] = qkv_b[i] * (i < DIM ? SCALE : 1.f);
    if (i < NH*NTOK*NTOK) {
        int h   = i >> 12;
        int qk2 = i & 4095;
        biasT[i] = rel_bias[rel_idx[qk2]*NH + h];
    }
}

// ---- fused window attention: one block = 4 windows, wave wv owns head wv ----
__global__ __launch_bounds__(384, 4) void winattn_kernel(
    const float* __restrict__ x,
    const float* __restrict__ proj_b,
    const u16* __restrict__ qw,
    const u16* __restrict__ pw,
    const float* __restrict__ qb2,
    const float* __restrict__ biasT,
    float* __restrict__ out)
{
    __shared__ __align__(16) u16 bufA[NTOK * AO_STR];  // 25600 B: QK h0-2 (3*4096) -> AO [64][200]
    __shared__ __align__(16) u16 bufB[NTOK * DIM];     // 24576 B: X swizzled [64][192]
    __shared__ __align__(16) u16 bufC[3 * NTOK * 64];  // 24576 B: QK h3-5

    const int tid  = threadIdx.x;
    const int wv   = tid >> 6;
    const int lane = tid & 63;
    const int l15  = lane & 15;
    const int g    = lane >> 4;

    const int b   = blockIdx.x & 7;          // image -> XCD
    const int grp = blockIdx.x >> 3;         // 0..195

    // gather geometry: thread -> (4 tokens of one window row, channels c0+24*it)
    const int qq   = tid & 15;
    const int trow = qq >> 1;
    const int tcol = (qq & 1) * 4;
    const int t0   = trow*8 + tcol;
    const int c0   = tid >> 4;

    const float* xb = x   + (size_t)b * DIM*IMG*IMG;
    float*       ob = out + (size_t)b * DIM*IMG*IMG;

    u16* Hh = (wv < 3) ? (bufA + wv*(NTOK*64)) : (bufC + (wv-3)*(NTOK*64));

    // per-thread gather pixel offset for window w
    auto gpix = [&](int w) -> size_t {
        int wi = w / NWIN, wj = w - wi*NWIN;
        int hh = wi*8 + trow + 4; if (hh >= IMG) hh -= IMG;
        int ww = wj*8 + tcol + 4; if (ww >= IMG) ww -= IMG;
        return (size_t)hh*IMG + ww;
    };

    v4f bufPA[4], bufPB[4];

    // X(u) -> bufB swizzled [64][192], feat ^ (tok&7)<<3
    auto writeX = [&]() {
        #pragma unroll
        for (int it = 0; it < 8; ++it) {
            v4f vv = (it < 4) ? bufPA[it] : bufPB[it-4];
            int c = c0 + it*24;
            #pragma unroll
            for (int i = 0; i < 4; ++i) {
                int tok = t0 + i;
                bufB[tok*DIM + (c ^ ((tok & 7) << 3))] = f2bf(vv[i]);
            }
        }
    };

    // ---------- prologue: gather window 0 ----------
    {
        size_t p0 = gpix(grp*WPB);
        #pragma unroll
        for (int it = 0; it < 4; ++it)
            bufPA[it] = *(const v4f*)(xb + (size_t)(c0 + it*24)*(IMG*IMG) + p0);
        #pragma unroll
        for (int it = 0; it < 4; ++it)
            bufPB[it] = *(const v4f*)(xb + (size_t)(c0 + (it+4)*24)*(IMG*IMG) + p0);
    }
    writeX();
    __syncthreads();

    #pragma unroll 1
    for (int u = 0; u < WPB; ++u) {
        const int w  = grp*WPB + u;
        const int wi = w / NWIN, wj = w - wi*NWIN;
        const size_t pnx = (u < WPB-1) ? gpix(w+1) : 0;

        // ---------- QKV GEMM in two 32-token halves; wave wv -> head wv ----------
        uint32_t vd[4][2][2];   // vd[mt][ntl][p] = V[16mt+4g+2p+{0,1}][ntl*16+l15]
        #pragma unroll
        for (int mh = 0; mh < 2; ++mh) {
            // issue half of next window's gather (hidden under MFMAs)
            if (u < WPB-1) {
                #pragma unroll
                for (int it = 0; it < 4; ++it) {
                    v4f ld = *(const v4f*)(xb + (size_t)(c0 + (mh*4+it)*24)*(IMG*IMG) + pnx);
                    if (mh == 0) bufPA[it] = ld; else bufPB[it] = ld;
                }
            }
            v4f acc[2][6];
            #pragma unroll
            for (int mt = 0; mt < 2; ++mt)
                #pragma unroll
                for (int nt = 0; nt < 6; ++nt)
                    acc[mt][nt] = (v4f){0.f,0.f,0.f,0.f};

            #pragma unroll
            for (int kk = 0; kk < 6; ++kk) {
                v8s afr[2];
                #pragma unroll
                for (int mt = 0; mt < 2; ++mt) {
                    int tok = mh*32 + mt*16 + l15;
                    afr[mt] = *(const v8s*)&bufB[tok*DIM + ((kk*32 + g*8) ^ ((tok & 7) << 3))];
                }
                #pragma unroll
                for (int nt = 0; nt < 6; ++nt) {
                    int o = (nt>>1)*DIM + wv*32 + (nt&1)*16 + l15;
                    v8s bfr = *(const v8s*)(qw + (size_t)o*DIM + kk*32 + g*8);
                    #pragma unroll
                    for (int mt = 0; mt < 2; ++mt)
                        acc[mt][nt] = __builtin_amdgcn_mfma_f32_16x16x32_bf16(afr[mt], bfr, acc[mt][nt], 0, 0, 0);
                }
            }
            // epilogue (this half): Q,K -> swizzled head tile; V -> packed regs
            #pragma unroll
            for (int ntl = 0; ntl < 2; ++ntl) {
                const int col = ntl*16 + l15;
                const float bq = qb2[wv*32 + col];
                const float bk = qb2[DIM + wv*32 + col];
                const float bv = qb2[2*DIM + wv*32 + col];
                #pragma unroll
                for (int mt = 0; mt < 2; ++mt) {
                    #pragma unroll
                    for (int r = 0; r < 4; ++r) {
                        const int tok = mh*32 + mt*16 + 4*g + r;
                        const int sw  = (tok & 7) << 3;
                        Hh[tok*64 + (col ^ sw)]        = f2bf(acc[mt][ntl][r]   + bq);
                        Hh[tok*64 + ((32 + col) ^ sw)] = f2bf(acc[mt][2+ntl][r] + bk);
                    }
                    vd[mh*2+mt][ntl][0] = pk2(acc[mt][4+ntl][0]+bv, acc[mt][4+ntl][1]+bv);
                    vd[mh*2+mt][ntl][1] = pk2(acc[mt][4+ntl][2]+bv, acc[mt][4+ntl][3]+bv);
                }
            }
        }

        // frag reads of own head (wave-private; must complete before S1)
        v8s qfr[4], kfr[4];
        #pragma unroll
        for (int t = 0; t < 4; ++t) {
            const int tok = t*16 + l15;
            const int sw  = (tok & 7) << 3;
            qfr[t] = *(const v8s*)&Hh[tok*64 + ((g*8) ^ sw)];
            kfr[t] = *(const v8s*)&Hh[tok*64 + ((32 + g*8) ^ sw)];
        }
        __syncthreads();   // S1: X reads + QK reads done

        // write next window's X (bufB free now)
        if (u < WPB-1) writeX();

        // ---------- attention (registers only) ----------
        // S^T = K Q^T : sacc[kt][qt][r] = S[key=16kt+4g+r][query=16qt+l15]
        v4f sacc[4][4];
        #pragma unroll
        for (int kt = 0; kt < 4; ++kt)
            #pragma unroll
            for (int qt = 0; qt < 4; ++qt)
                sacc[kt][qt] = __builtin_amdgcn_mfma_f32_16x16x32_bf16(kfr[kt], qfr[qt],
                                    (v4f){0.f,0.f,0.f,0.f}, 0, 0, 0);

        const float* bt = biasT + wv*(NTOK*NTOK);
        #pragma unroll
        for (int qt = 0; qt < 4; ++qt) {
            #pragma unroll
            for (int kt = 0; kt < 4; ++kt) {
                v4f bb = *(const v4f*)&bt[(qt*16 + l15)*NTOK + kt*16 + 4*g];
                sacc[kt][qt] += bb;
            }
            float mx = sacc[0][qt][0];
            #pragma unroll
            for (int kt = 0; kt < 4; ++kt)
                #pragma unroll
                for (int r = 0; r < 4; ++r) mx = fmaxf(mx, sacc[kt][qt][r]);
            mx = fmaxf(mx, __shfl_xor(mx, 16));
            mx = fmaxf(mx, __shfl_xor(mx, 32));
            float sum = 0.f;
            #pragma unroll
            for (int kt = 0; kt < 4; ++kt)
                #pragma unroll
                for (int r = 0; r < 4; ++r) {
                    float e = __expf(sacc[kt][qt][r] - mx);
                    sacc[kt][qt][r] = e; sum += e;
                }
            sum += __shfl_xor(sum, 16);
            sum += __shfl_xor(sum, 32);
            float inv = 1.f / sum;
            #pragma unroll
            for (int kt = 0; kt < 4; ++kt)
                #pragma unroll
                for (int r = 0; r < 4; ++r) sacc[kt][qt][r] *= inv;
        }

        // pack P to bf16 early (frees sacc before PV)
        uint32_t pd[2][4][4];
        #pragma unroll
        for (int kk = 0; kk < 2; ++kk)
            #pragma unroll
            for (int qt = 0; qt < 4; ++qt) {
                pd[kk][qt][0] = pk2(sacc[2*kk  ][qt][0], sacc[2*kk  ][qt][1]);
                pd[kk][qt][1] = pk2(sacc[2*kk  ][qt][2], sacc[2*kk  ][qt][3]);
                pd[kk][qt][2] = pk2(sacc[2*kk+1][qt][0], sacc[2*kk+1][qt][1]);
                pd[kk][qt][3] = pk2(sacc[2*kk+1][qt][2], sacc[2*kk+1][qt][3]);
            }

        // O^T = V^T P^T (pure register repacks; slot (g,j) <-> key 16*(2kk+(j>>2))+4g+(j&3))
        v4f oT[2][4];
        #pragma unroll
        for (int ntl = 0; ntl < 2; ++ntl)
            #pragma unroll
            for (int qt = 0; qt < 4; ++qt)
                oT[ntl][qt] = (v4f){0.f,0.f,0.f,0.f};
        #pragma unroll
        for (int kk = 0; kk < 2; ++kk) {
            v8s vfr[2];
            #pragma unroll
            for (int ntl = 0; ntl < 2; ++ntl) {
                union { v8s v; uint32_t d[4]; } uu;
                uu.d[0] = vd[2*kk  ][ntl][0]; uu.d[1] = vd[2*kk  ][ntl][1];
                uu.d[2] = vd[2*kk+1][ntl][0]; uu.d[3] = vd[2*kk+1][ntl][1];
                vfr[ntl] = uu.v;
            }
            #pragma unroll
            for (int qt = 0; qt < 4; ++qt) {
                union { v8s v; uint32_t d[4]; } p;
                p.d[0] = pd[kk][qt][0]; p.d[1] = pd[kk][qt][1];
                p.d[2] = pd[kk][qt][2]; p.d[3] = pd[kk][qt][3];
                #pragma unroll
                for (int ntl = 0; ntl < 2; ++ntl)
                    oT[ntl][qt] = __builtin_amdgcn_mfma_f32_16x16x32_bf16(vfr[ntl], p.v, oT[ntl][qt], 0, 0, 0);
            }
        }

        // attn_out -> bufA [64][AO_STR], b64 stores
        #pragma unroll
        for (int qt = 0; qt < 4; ++qt)
            #pragma unroll
            for (int ntl = 0; ntl < 2; ++ntl) {
                v2u o;
                o.x = pk2(oT[ntl][qt][0], oT[ntl][qt][1]);
                o.y = pk2(oT[ntl][qt][2], oT[ntl][qt][3]);
                *(v2u*)&bufA[(qt*16 + l15)*AO_STR + wv*32 + ntl*16 + 4*g] = o;
            }
        __syncthreads();   // S2: AO + next-X published

        // ---------- transposed proj GEMM + direct register scatter ----------
        v4f pacc[2][4];
        #pragma unroll
        for (int ntl = 0; ntl < 2; ++ntl)
            #pragma unroll
            for (int qt = 0; qt < 4; ++qt)
                pacc[ntl][qt] = (v4f){0.f,0.f,0.f,0.f};
        #pragma unroll
        for (int kk = 0; kk < 6; ++kk) {
            v8s aofr[4];
            #pragma unroll
            for (int qt = 0; qt < 4; ++qt)
                aofr[qt] = *(const v8s*)&bufA[(qt*16 + l15)*AO_STR + kk*32 + g*8];
            #pragma unroll
            for (int ntl = 0; ntl < 2; ++ntl) {
                v8s pwfr = *(const v8s*)(pw + (size_t)(wv*32 + ntl*16 + l15)*DIM + kk*32 + g*8);
                #pragma unroll
                for (int qt = 0; qt < 4; ++qt)
                    pacc[ntl][qt] = __builtin_amdgcn_mfma_f32_16x16x32_bf16(pwfr, aofr[qt], pacc[ntl][qt], 0, 0, 0);
            }
        }
        #pragma unroll
        for (int qt = 0; qt < 4; ++qt) {
            const int strow = 2*qt + (l15 >> 3);
            const int stcol = l15 & 7;
            int hh = wi*8 + strow + 4; if (hh >= IMG) hh -= IMG;
            int ww = wj*8 + stcol + 4; if (ww >= IMG) ww -= IMG;
            const size_t pix = (size_t)hh*IMG + ww;
            #pragma unroll
            for (int ntl = 0; ntl < 2; ++ntl)
                #pragma unroll
                for (int r = 0; r < 4; ++r) {
                    const int c = wv*32 + ntl*16 + 4*g + r;
                    ob[(size_t)c*(IMG*IMG) + pix] = pacc[ntl][qt][r] + proj_b[c];
                }
        }
        __syncthreads();   // S3: AO reads done -> next window may overwrite bufA
    }
}

extern "C" void kernel_launch(void* const* d_in, const int* in_sizes, int n_in,
                              void* d_out, int out_size, void* d_ws, size_t ws_size,
                              hipStream_t stream) {
    const float* x        = (const float*)d_in[0];
    const float* qkv_w    = (const float*)d_in[1];
    const float* qkv_b    = (const float*)d_in[2];
    const float* proj_w   = (const float*)d_in[3];
    const float* proj_b   = (const float*)d_in[4];
    const float* rel_bias = (const float*)d_in[5];
    const int*   rel_idx  = (const int*)d_in[6];

    u16*   qw_bf  = (u16*)d_ws;                         // 221184 B
    u16*   pw_bf  = (u16*)((char*)d_ws + 221184);       //  73728 B
    float* qb2    = (float*)((char*)d_ws + 294912);     //   2304 B
    float* biasT  = (float*)((char*)d_ws + 297216);     //  98304 B
    float* out    = (float*)d_out;

    hipLaunchKernelGGL(prep_kernel, dim3(432), dim3(256), 0, stream,
                       qkv_w, qkv_b, proj_w, rel_bias, rel_idx, qw_bf, pw_bf, qb2, biasT);
    hipLaunchKernelGGL(winattn_kernel, dim3(NB*NGRP), dim3(384), 0, stream,
                       x, proj_b, qw_bf, pw_bf, qb2, biasT, out);
}

// Round 7
// 731.089 us; speedup vs baseline: 2.3239x; 2.3239x over previous
//
#include <hip/hip_runtime.h>
#include <stdint.h>

typedef unsigned short u16;
typedef short v8s __attribute__((ext_vector_type(8)));
typedef float v4f __attribute__((ext_vector_type(4)));
typedef uint32_t v2u __attribute__((ext_vector_type(2)));

#define DIM 192
#define NH 6
#define NTOK 64
#define IMG 224
#define NWIN 28
#define NB 8
#define NWINDOWS (NB*NWIN*NWIN)
#define SCALE 0.17677669529663687f
#define AO_STR 200   // bf16 stride for attn_out tile

__device__ __forceinline__ u16 f2bf(float f) {
    union { float f; uint32_t u; } v; v.f = f;
    return (u16)((v.u + 0x7FFFu + ((v.u >> 16) & 1u)) >> 16);
}
__device__ __forceinline__ uint32_t pk2(float lo, float hi) {
    return (uint32_t)f2bf(lo) | ((uint32_t)f2bf(hi) << 16);
}

// ---- prep: bf16 weights (SCALE folded into q rows), scaled bias, expanded bias table ----
__global__ void prep_kernel(const float* __restrict__ qkv_w,
                            const float* __restrict__ qkv_b,
                            const float* __restrict__ proj_w,
                            const float* __restrict__ rel_bias,
                            const int* __restrict__ rel_idx,
                            u16* __restrict__ qw, u16* __restrict__ pw,
                            float* __restrict__ qb2, float* __restrict__ biasT) {
    int i = blockIdx.x * 256 + threadIdx.x;
    if (i < 3*DIM*DIM) {
        float s = (i < DIM*DIM) ? SCALE : 1.f;
        qw[i] = f2bf(qkv_w[i] * s);
    }
    if (i < DIM*DIM) pw[i] = f2bf(proj_w[i]);
    if (i < 3*DIM)   qb2[i] = qkv_b[i] * (i < DIM ? SCALE : 1.f);
    if (i < NH*NTOK*NTOK) {
        int h   = i >> 12;
        int qk2 = i & 4095;
        biasT[i] = rel_bias[rel_idx[qk2]*NH + h];
    }
}

// ---- fused window attention: one block per window, wave wv owns head wv ----
__global__ __launch_bounds__(384, 3) void winattn_kernel(
    const float* __restrict__ x,
    const float* __restrict__ proj_b,
    const u16* __restrict__ qw,
    const u16* __restrict__ pw,
    const float* __restrict__ qb2,
    const float* __restrict__ biasT,
    float* __restrict__ out)
{
    __shared__ __align__(16) u16 bufX[NTOK * DIM];     // 24576 B: X swizzled [64][192]
    __shared__ __align__(16) u16 bufA[NTOK * AO_STR];  // 25600 B: QK h0-2 (3*4096) -> AO [64][200]
    __shared__ __align__(16) u16 bufC[3 * NTOK * 64];  // 24576 B: QK h3-5        (total 74752 B)

    const int tid  = threadIdx.x;
    const int wv   = tid >> 6;
    const int lane = tid & 63;
    const int l15  = lane & 15;
    const int g    = lane >> 4;

    // XCD swizzle: dispatch i -> XCD i%8; each XCD gets one full image
    const int b  = blockIdx.x & 7;
    const int rm = blockIdx.x >> 3;
    const int wi = rm / NWIN;
    const int wj = rm % NWIN;

    // gather geometry: thread -> (4 tokens of one window row, channels c0+24*it)
    const int qq   = tid & 15;
    const int trow = qq >> 1;
    const int tcol = (qq & 1) * 4;
    const int t0   = trow*8 + tcol;
    const int c0   = tid >> 4;
    int ghh = wi*8 + trow + 4; if (ghh >= IMG) ghh -= IMG;   // roll(-4) folded in
    int gww = wj*8 + tcol + 4; if (gww >= IMG) gww -= IMG;   // 16B vector never straddles wrap
    const size_t pixoff = (size_t)ghh*IMG + gww;

    u16* Hh = (wv < 3) ? (bufA + wv*(NTOK*64)) : (bufC + (wv-3)*(NTOK*64));

    // ---------- phase 0: gather (float4) -> bufX swizzled [64][192], feat ^ (tok&7)<<3 ----------
    const float* xb = x + (size_t)b * DIM*IMG*IMG;
    {
        v4f buf[8];
        #pragma unroll
        for (int it = 0; it < 8; ++it)
            buf[it] = *(const v4f*)(xb + (size_t)(c0 + it*24)*(IMG*IMG) + pixoff);
        #pragma unroll
        for (int it = 0; it < 8; ++it) {
            int c = c0 + it*24;
            #pragma unroll
            for (int i = 0; i < 4; ++i) {
                int tok = t0 + i;
                bufX[tok*DIM + (c ^ ((tok & 7) << 3))] = f2bf(buf[it][i]);
            }
        }
    }
    __syncthreads();   // B1

    // ---------- phase 1: QKV GEMM in two 32-token halves; wave wv -> head wv ----------
    uint32_t vd[4][2][2];   // vd[mt4][ntl][p] = V[16*mt4+4g+2p+{0,1}][ntl*16+l15]
    #pragma unroll
    for (int mh = 0; mh < 2; ++mh) {
        v4f acc[2][6];
        #pragma unroll
        for (int mt = 0; mt < 2; ++mt)
            #pragma unroll
            for (int nt = 0; nt < 6; ++nt)
                acc[mt][nt] = (v4f){0.f,0.f,0.f,0.f};

        #pragma unroll
        for (int kk = 0; kk < 6; ++kk) {
            v8s afr[2];
            #pragma unroll
            for (int mt = 0; mt < 2; ++mt) {
                int tok = mh*32 + mt*16 + l15;
                afr[mt] = *(const v8s*)&bufX[tok*DIM + ((kk*32 + g*8) ^ ((tok & 7) << 3))];
            }
            #pragma unroll
            for (int nt = 0; nt < 6; ++nt) {
                int o = (nt>>1)*DIM + wv*32 + (nt&1)*16 + l15;
                v8s bfr = *(const v8s*)(qw + (size_t)o*DIM + kk*32 + g*8);
                #pragma unroll
                for (int mt = 0; mt < 2; ++mt)
                    acc[mt][nt] = __builtin_amdgcn_mfma_f32_16x16x32_bf16(afr[mt], bfr, acc[mt][nt], 0, 0, 0);
            }
        }
        // epilogue (this half): Q,K -> swizzled head tile (wave-private); V -> packed regs
        #pragma unroll
        for (int ntl = 0; ntl < 2; ++ntl) {
            const int col = ntl*16 + l15;
            const float bq = qb2[wv*32 + col];
            const float bk = qb2[DIM + wv*32 + col];
            const float bv = qb2[2*DIM + wv*32 + col];
            #pragma unroll
            for (int mt = 0; mt < 2; ++mt) {
                #pragma unroll
                for (int r = 0; r < 4; ++r) {
                    const int tok = mh*32 + mt*16 + 4*g + r;
                    const int sw  = (tok & 7) << 3;
                    Hh[tok*64 + (col ^ sw)]        = f2bf(acc[mt][ntl][r]   + bq);
                    Hh[tok*64 + ((32 + col) ^ sw)] = f2bf(acc[mt][2+ntl][r] + bk);
                }
                vd[mh*2+mt][ntl][0] = pk2(acc[mt][4+ntl][0]+bv, acc[mt][4+ntl][1]+bv);
                vd[mh*2+mt][ntl][1] = pk2(acc[mt][4+ntl][2]+bv, acc[mt][4+ntl][3]+bv);
            }
        }
    }

    // frag reads of own head (wave-private; same-wave LDS ordering, no barrier needed)
    v8s qfr[4], kfr[4];
    #pragma unroll
    for (int t = 0; t < 4; ++t) {
        const int tok = t*16 + l15;
        const int sw  = (tok & 7) << 3;
        qfr[t] = *(const v8s*)&Hh[tok*64 + ((g*8) ^ sw)];
        kfr[t] = *(const v8s*)&Hh[tok*64 + ((32 + g*8) ^ sw)];
    }
    __syncthreads();   // B2: all QK frag reads done -> AO may overwrite bufA

    // ---------- phase 2: attention (registers only) ----------
    // S^T = K Q^T : sacc[kt][qt][r] = S[key=16kt+4g+r][query=16qt+l15]
    v4f sacc[4][4];
    #pragma unroll
    for (int kt = 0; kt < 4; ++kt)
        #pragma unroll
        for (int qt = 0; qt < 4; ++qt)
            sacc[kt][qt] = __builtin_amdgcn_mfma_f32_16x16x32_bf16(kfr[kt], qfr[qt],
                                (v4f){0.f,0.f,0.f,0.f}, 0, 0, 0);

    // + bias (float4), softmax over keys: 16 in-lane + shfl_xor(16,32)
    const float* bt = biasT + wv*(NTOK*NTOK);
    #pragma unroll
    for (int qt = 0; qt < 4; ++qt) {
        #pragma unroll
        for (int kt = 0; kt < 4; ++kt) {
            v4f bb = *(const v4f*)&bt[(qt*16 + l15)*NTOK + kt*16 + 4*g];
            sacc[kt][qt] += bb;
        }
        float mx = sacc[0][qt][0];
        #pragma unroll
        for (int kt = 0; kt < 4; ++kt)
            #pragma unroll
            for (int r = 0; r < 4; ++r) mx = fmaxf(mx, sacc[kt][qt][r]);
        mx = fmaxf(mx, __shfl_xor(mx, 16));
        mx = fmaxf(mx, __shfl_xor(mx, 32));
        float sum = 0.f;
        #pragma unroll
        for (int kt = 0; kt < 4; ++kt)
            #pragma unroll
            for (int r = 0; r < 4; ++r) {
                float e = __expf(sacc[kt][qt][r] - mx);
                sacc[kt][qt][r] = e; sum += e;
            }
        sum += __shfl_xor(sum, 16);
        sum += __shfl_xor(sum, 32);
        float inv = 1.f / sum;
        #pragma unroll
        for (int kt = 0; kt < 4; ++kt)
            #pragma unroll
            for (int r = 0; r < 4; ++r) sacc[kt][qt][r] *= inv;
    }

    // O^T = V^T P^T via pure register repacks. Slot convention on BOTH operands:
    // slot (g,j) of kk-th MFMA holds key 16*(2kk+(j>>2)) + 4g + (j&3).
    v4f oT[2][4];   // [ntl][qt]: O[query=16qt+l15][d=16ntl+4g+r]
    #pragma unroll
    for (int ntl = 0; ntl < 2; ++ntl)
        #pragma unroll
        for (int qt = 0; qt < 4; ++qt)
            oT[ntl][qt] = (v4f){0.f,0.f,0.f,0.f};
    #pragma unroll
    for (int kk = 0; kk < 2; ++kk) {
        v8s vfr[2];
        #pragma unroll
        for (int ntl = 0; ntl < 2; ++ntl) {
            union { v8s v; uint32_t d[4]; } uu;
            uu.d[0] = vd[2*kk  ][ntl][0]; uu.d[1] = vd[2*kk  ][ntl][1];
            uu.d[2] = vd[2*kk+1][ntl][0]; uu.d[3] = vd[2*kk+1][ntl][1];
            vfr[ntl] = uu.v;
        }
        #pragma unroll
        for (int qt = 0; qt < 4; ++qt) {
            union { v8s v; uint32_t d[4]; } p;
            p.d[0] = pk2(sacc[2*kk  ][qt][0], sacc[2*kk  ][qt][1]);
            p.d[1] = pk2(sacc[2*kk  ][qt][2], sacc[2*kk  ][qt][3]);
            p.d[2] = pk2(sacc[2*kk+1][qt][0], sacc[2*kk+1][qt][1]);
            p.d[3] = pk2(sacc[2*kk+1][qt][2], sacc[2*kk+1][qt][3]);
            #pragma unroll
            for (int ntl = 0; ntl < 2; ++ntl)
                oT[ntl][qt] = __builtin_amdgcn_mfma_f32_16x16x32_bf16(vfr[ntl], p.v, oT[ntl][qt], 0, 0, 0);
        }
    }

    // attn_out -> bufA [64][AO_STR], b64 stores (4 consecutive feats per lane)
    #pragma unroll
    for (int qt = 0; qt < 4; ++qt)
        #pragma unroll
        for (int ntl = 0; ntl < 2; ++ntl) {
            v2u o;
            o.x = pk2(oT[ntl][qt][0], oT[ntl][qt][1]);
            o.y = pk2(oT[ntl][qt][2], oT[ntl][qt][3]);
            *(v2u*)&bufA[(qt*16 + l15)*AO_STR + wv*32 + ntl*16 + 4*g] = o;
        }
    __syncthreads();   // B3: AO complete

    // ---------- phase 3: transposed proj GEMM + direct register scatter ----------
    v4f pacc[2][4];    // [ntl][qt]: P[out=wv*32+16ntl+4g+r][tok=16qt+l15]
    #pragma unroll
    for (int ntl = 0; ntl < 2; ++ntl)
        #pragma unroll
        for (int qt = 0; qt < 4; ++qt)
            pacc[ntl][qt] = (v4f){0.f,0.f,0.f,0.f};
    #pragma unroll
    for (int kk = 0; kk < 6; ++kk) {
        v8s aofr[4];
        #pragma unroll
        for (int qt = 0; qt < 4; ++qt)
            aofr[qt] = *(const v8s*)&bufA[(qt*16 + l15)*AO_STR + kk*32 + g*8];
        #pragma unroll
        for (int ntl = 0; ntl < 2; ++ntl) {
            v8s pwfr = *(const v8s*)(pw + (size_t)(wv*32 + ntl*16 + l15)*DIM + kk*32 + g*8);
            #pragma unroll
            for (int qt = 0; qt < 4; ++qt)
                pacc[ntl][qt] = __builtin_amdgcn_mfma_f32_16x16x32_bf16(pwfr, aofr[qt], pacc[ntl][qt], 0, 0, 0);
        }
    }
    // bias + scatter straight from registers (32B row segments, roll(+4) == gather pixels)
    float pb[2][4];
    #pragma unroll
    for (int ntl = 0; ntl < 2; ++ntl)
        #pragma unroll
        for (int r = 0; r < 4; ++r)
            pb[ntl][r] = proj_b[wv*32 + ntl*16 + 4*g + r];

    float* ob = out + (size_t)b * DIM*IMG*IMG;
    #pragma unroll
    for (int qt = 0; qt < 4; ++qt) {
        const int strow = 2*qt + (l15 >> 3);
        const int stcol = l15 & 7;
        int hh = wi*8 + strow + 4; if (hh >= IMG) hh -= IMG;
        int ww = wj*8 + stcol + 4; if (ww >= IMG) ww -= IMG;
        const size_t pix = (size_t)hh*IMG + ww;
        #pragma unroll
        for (int ntl = 0; ntl < 2; ++ntl)
            #pragma unroll
            for (int r = 0; r < 4; ++r) {
                const int c = wv*32 + ntl*16 + 4*g + r;
                ob[(size_t)c*(IMG*IMG) + pix] = pacc[ntl][qt][r] + pb[ntl][r];
            }
    }
}

extern "C" void kernel_launch(void* const* d_in, const int* in_sizes, int n_in,
                              void* d_out, int out_size, void* d_ws, size_t ws_size,
                              hipStream_t stream) {
    const float* x        = (const float*)d_in[0];
    const float* qkv_w    = (const float*)d_in[1];
    const float* qkv_b    = (const float*)d_in[2];
    const float* proj_w   = (const float*)d_in[3];
    const float* proj_b   = (const float*)d_in[4];
    const float* rel_bias = (const float*)d_in[5];
    const int*   rel_idx  = (const int*)d_in[6];

    u16*   qw_bf  = (u16*)d_ws;                         // 221184 B
    u16*   pw_bf  = (u16*)((char*)d_ws + 221184);       //  73728 B
    float* qb2    = (float*)((char*)d_ws + 294912);     //   2304 B
    float* biasT  = (float*)((char*)d_ws + 297216);     //  98304 B
    float* out    = (float*)d_out;

    hipLaunchKernelGGL(prep_kernel, dim3(432), dim3(256), 0, stream,
                       qkv_w, qkv_b, proj_w, rel_bias, rel_idx, qw_bf, pw_bf, qb2, biasT);
    hipLaunchKernelGGL(winattn_kernel, dim3(NWINDOWS), dim3(384), 0, stream,
                       x, proj_b, qw_bf, pw_bf, qb2, biasT, out);
}

// Round 8
// 633.531 us; speedup vs baseline: 2.6818x; 1.1540x over previous
//
#include <hip/hip_runtime.h>
#include <hip/hip_bf16.h>
#include <stdint.h>

typedef unsigned short u16;
typedef short v8s __attribute__((ext_vector_type(8)));
typedef float v4f __attribute__((ext_vector_type(4)));
typedef uint32_t v2u __attribute__((ext_vector_type(2)));

#define DIM 192
#define NH 6
#define IMG 224
#define NWIN 28
#define NB 8
#define NWINDOWS (NB*NWIN*NWIN)
#define SCALE 0.17677669529663687f
#define AO_STR 200   // bf16 stride for attn_out tile (dword stride ≡4 mod 32: 2-way free)

__device__ __forceinline__ u16 f2bf(float f) {
    union { __hip_bfloat16 b; u16 u; } c; c.b = __float2bfloat16(f); return c.u;
}
__device__ __forceinline__ uint32_t pk2(float lo, float hi) {
    union { __hip_bfloat162 b; uint32_t u; } c;
    c.b = __float22bfloat162_rn(make_float2(lo, hi));
    return c.u;
}

// ---- prep: bf16 weights (SCALE folded into q rows), scaled bias, expanded bias table ----
__global__ void prep_kernel(const float* __restrict__ qkv_w,
                            const float* __restrict__ qkv_b,
                            const float* __restrict__ proj_w,
                            const float* __restrict__ rel_bias,
                            const int* __restrict__ rel_idx,
                            u16* __restrict__ qw, u16* __restrict__ pw,
                            float* __restrict__ qb2, float* __restrict__ biasT) {
    int i = blockIdx.x * 256 + threadIdx.x;
    if (i < 3*DIM*DIM) {
        float s = (i < DIM*DIM) ? SCALE : 1.f;
        qw[i] = f2bf(qkv_w[i] * s);
    }
    if (i < DIM*DIM) pw[i] = f2bf(proj_w[i]);
    if (i < 3*DIM)   qb2[i] = qkv_b[i] * (i < DIM ? SCALE : 1.f);
    if (i < NH*64*64) {
        int h   = i >> 12;          // biasT[h][query][key], key minor
        int qk2 = i & 4095;
        biasT[i] = rel_bias[rel_idx[qk2]*NH + h];
    }
}

// ---- fused window attention: one block per window, wave wv owns head wv ----
__global__ __launch_bounds__(384, 3) void winattn_kernel(
    const float* __restrict__ x,
    const float* __restrict__ proj_b,
    const u16* __restrict__ qw,
    const u16* __restrict__ pw,
    const float* __restrict__ qb2,
    const float* __restrict__ biasT,
    float* __restrict__ out)
{
    __shared__ __align__(16) u16 bufX[64 * DIM];     // 24576 B: X swizzled [64][192]
    __shared__ __align__(16) u16 bufO[64 * AO_STR];  // 25600 B: attn_out [64][200]   (total 50176 B)

    const int tid  = threadIdx.x;
    const int wv   = tid >> 6;
    const int lane = tid & 63;
    const int l15  = lane & 15;
    const int g    = lane >> 4;

    // XCD swizzle: dispatch i -> XCD i%8; each XCD gets one full image
    const int b  = blockIdx.x & 7;
    const int rm = blockIdx.x >> 3;
    const int wi = rm / NWIN;
    const int wj = rm % NWIN;

    // gather geometry: thread -> (4 tokens of one window row, channels c0+24*it)
    const int qq   = tid & 15;
    const int trow = qq >> 1;
    const int tcol = (qq & 1) * 4;
    const int t0   = trow*8 + tcol;
    const int c0   = tid >> 4;
    int ghh = wi*8 + trow + 4; if (ghh >= IMG) ghh -= IMG;   // roll(-4) folded in
    int gww = wj*8 + tcol + 4; if (gww >= IMG) gww -= IMG;   // 16B vector never straddles wrap
    const size_t pixoff = (size_t)ghh*IMG + gww;

    // ---------- phase 0: gather (float4) -> bufX swizzled [64][192], feat ^ (tok&7)<<3 ----------
    const float* xb = x + (size_t)b * DIM*IMG*IMG;
    {
        v4f buf[8];
        #pragma unroll
        for (int it = 0; it < 8; ++it)
            buf[it] = *(const v4f*)(xb + (size_t)(c0 + it*24)*(IMG*IMG) + pixoff);
        #pragma unroll
        for (int it = 0; it < 8; ++it) {
            int c = c0 + it*24;
            #pragma unroll
            for (int i = 0; i < 4; ++i) {
                int tok = t0 + i;
                bufX[tok*DIM + (c ^ ((tok & 7) << 3))] = f2bf(buf[it][i]);
            }
        }
    }
    __syncthreads();   // B1: X published

    // ---------- phase 1a: fused transposed Q^T,K^T GEMM ----------
    // C layout: lane = token (col), regs = features (row = ntl*16 + 4g + r)
    v4f qacc[2][4], kacc[2][4];
    #pragma unroll
    for (int ntl = 0; ntl < 2; ++ntl)
        #pragma unroll
        for (int qt = 0; qt < 4; ++qt) {
            qacc[ntl][qt] = (v4f){0.f,0.f,0.f,0.f};
            kacc[ntl][qt] = (v4f){0.f,0.f,0.f,0.f};
        }
    #pragma unroll
    for (int kk = 0; kk < 6; ++kk) {
        v8s xfr[4];
        #pragma unroll
        for (int qt = 0; qt < 4; ++qt) {
            int tok = qt*16 + l15;
            xfr[qt] = *(const v8s*)&bufX[tok*DIM + ((kk*32 + g*8) ^ ((tok & 7) << 3))];
        }
        #pragma unroll
        for (int ntl = 0; ntl < 2; ++ntl) {
            int o = wv*32 + ntl*16 + l15;
            v8s wq = *(const v8s*)(qw + (size_t)o*DIM + kk*32 + g*8);
            v8s wk = *(const v8s*)(qw + (size_t)(DIM + o)*DIM + kk*32 + g*8);
            #pragma unroll
            for (int qt = 0; qt < 4; ++qt) {
                qacc[ntl][qt] = __builtin_amdgcn_mfma_f32_16x16x32_bf16(wq, xfr[qt], qacc[ntl][qt], 0, 0, 0);
                kacc[ntl][qt] = __builtin_amdgcn_mfma_f32_16x16x32_bf16(wk, xfr[qt], kacc[ntl][qt], 0, 0, 0);
            }
        }
    }
    // epilogue: bias along regs, pack straight into S-operand frags (sigma2 slot map:
    // slot (g,j) <-> feature 16*(j>>2) + 4g + (j&3)) — pure in-lane repack, no LDS
    v8s qfr[4], kfr[4];
    {
        v4f bqv[2], bkv[2];
        #pragma unroll
        for (int ntl = 0; ntl < 2; ++ntl) {
            bqv[ntl] = *(const v4f*)&qb2[wv*32 + ntl*16 + 4*g];
            bkv[ntl] = *(const v4f*)&qb2[DIM + wv*32 + ntl*16 + 4*g];
        }
        #pragma unroll
        for (int qt = 0; qt < 4; ++qt) {
            union { v8s v; uint32_t d[4]; } uq, uk;
            uq.d[0] = pk2(qacc[0][qt][0]+bqv[0][0], qacc[0][qt][1]+bqv[0][1]);
            uq.d[1] = pk2(qacc[0][qt][2]+bqv[0][2], qacc[0][qt][3]+bqv[0][3]);
            uq.d[2] = pk2(qacc[1][qt][0]+bqv[1][0], qacc[1][qt][1]+bqv[1][1]);
            uq.d[3] = pk2(qacc[1][qt][2]+bqv[1][2], qacc[1][qt][3]+bqv[1][3]);
            uk.d[0] = pk2(kacc[0][qt][0]+bkv[0][0], kacc[0][qt][1]+bkv[0][1]);
            uk.d[1] = pk2(kacc[0][qt][2]+bkv[0][2], kacc[0][qt][3]+bkv[0][3]);
            uk.d[2] = pk2(kacc[1][qt][0]+bkv[1][0], kacc[1][qt][1]+bkv[1][1]);
            uk.d[3] = pk2(kacc[1][qt][2]+bkv[1][2], kacc[1][qt][3]+bkv[1][3]);
            qfr[qt] = uq.v;
            kfr[qt] = uk.v;
        }
    }

    // ---------- phase 1b: V GEMM (normal orientation, r5-proven) ----------
    uint32_t vd[4][2][2];   // vd[mt][ntl][p] = V[16mt+4g+2p+{0,1}][ntl*16+l15]
    {
        v4f vacc[4][2];
        #pragma unroll
        for (int mt = 0; mt < 4; ++mt)
            #pragma unroll
            for (int ntl = 0; ntl < 2; ++ntl)
                vacc[mt][ntl] = (v4f){0.f,0.f,0.f,0.f};
        #pragma unroll
        for (int kk = 0; kk < 6; ++kk) {
            v8s xfr[4];
            #pragma unroll
            for (int mt = 0; mt < 4; ++mt) {
                int tok = mt*16 + l15;
                xfr[mt] = *(const v8s*)&bufX[tok*DIM + ((kk*32 + g*8) ^ ((tok & 7) << 3))];
            }
            #pragma unroll
            for (int ntl = 0; ntl < 2; ++ntl) {
                int o = 2*DIM + wv*32 + ntl*16 + l15;
                v8s wvf = *(const v8s*)(qw + (size_t)o*DIM + kk*32 + g*8);
                #pragma unroll
                for (int mt = 0; mt < 4; ++mt)
                    vacc[mt][ntl] = __builtin_amdgcn_mfma_f32_16x16x32_bf16(xfr[mt], wvf, vacc[mt][ntl], 0, 0, 0);
            }
        }
        #pragma unroll
        for (int ntl = 0; ntl < 2; ++ntl) {
            const float bv = qb2[2*DIM + wv*32 + ntl*16 + l15];
            #pragma unroll
            for (int mt = 0; mt < 4; ++mt) {
                vd[mt][ntl][0] = pk2(vacc[mt][ntl][0]+bv, vacc[mt][ntl][1]+bv);
                vd[mt][ntl][1] = pk2(vacc[mt][ntl][2]+bv, vacc[mt][ntl][3]+bv);
            }
        }
    }

    // ---------- phase 2: attention (registers only; r5-proven) ----------
    // S^T = K Q^T : sacc[kt][qt][r] = S[key=16kt+4g+r][query=16qt+l15]
    v4f sacc[4][4];
    #pragma unroll
    for (int kt = 0; kt < 4; ++kt)
        #pragma unroll
        for (int qt = 0; qt < 4; ++qt)
            sacc[kt][qt] = __builtin_amdgcn_mfma_f32_16x16x32_bf16(kfr[kt], qfr[qt],
                                (v4f){0.f,0.f,0.f,0.f}, 0, 0, 0);

    const float* bt = biasT + wv*4096;
    #pragma unroll
    for (int qt = 0; qt < 4; ++qt) {
        #pragma unroll
        for (int kt = 0; kt < 4; ++kt) {
            v4f bb = *(const v4f*)&bt[(qt*16 + l15)*64 + kt*16 + 4*g];
            sacc[kt][qt] += bb;
        }
        float mx = sacc[0][qt][0];
        #pragma unroll
        for (int kt = 0; kt < 4; ++kt)
            #pragma unroll
            for (int r = 0; r < 4; ++r) mx = fmaxf(mx, sacc[kt][qt][r]);
        mx = fmaxf(mx, __shfl_xor(mx, 16));
        mx = fmaxf(mx, __shfl_xor(mx, 32));
        float sum = 0.f;
        #pragma unroll
        for (int kt = 0; kt < 4; ++kt)
            #pragma unroll
            for (int r = 0; r < 4; ++r) {
                float e = __expf(sacc[kt][qt][r] - mx);
                sacc[kt][qt][r] = e; sum += e;
            }
        sum += __shfl_xor(sum, 16);
        sum += __shfl_xor(sum, 32);
        float inv = 1.f / sum;
        #pragma unroll
        for (int kt = 0; kt < 4; ++kt)
            #pragma unroll
            for (int r = 0; r < 4; ++r) sacc[kt][qt][r] *= inv;
    }

    // O^T = V^T P^T via register repacks; slot (g,j) <-> key 16*(2kk+(j>>2))+4g+(j&3)
    v4f oT[2][4];   // [ntl][qt]: O[query=16qt+l15][d=16ntl+4g+r]
    #pragma unroll
    for (int ntl = 0; ntl < 2; ++ntl)
        #pragma unroll
        for (int qt = 0; qt < 4; ++qt)
            oT[ntl][qt] = (v4f){0.f,0.f,0.f,0.f};
    #pragma unroll
    for (int kk = 0; kk < 2; ++kk) {
        v8s vfr[2];
        #pragma unroll
        for (int ntl = 0; ntl < 2; ++ntl) {
            union { v8s v; uint32_t d[4]; } uu;
            uu.d[0] = vd[2*kk  ][ntl][0]; uu.d[1] = vd[2*kk  ][ntl][1];
            uu.d[2] = vd[2*kk+1][ntl][0]; uu.d[3] = vd[2*kk+1][ntl][1];
            vfr[ntl] = uu.v;
        }
        #pragma unroll
        for (int qt = 0; qt < 4; ++qt) {
            union { v8s v; uint32_t d[4]; } p;
            p.d[0] = pk2(sacc[2*kk  ][qt][0], sacc[2*kk  ][qt][1]);
            p.d[1] = pk2(sacc[2*kk  ][qt][2], sacc[2*kk  ][qt][3]);
            p.d[2] = pk2(sacc[2*kk+1][qt][0], sacc[2*kk+1][qt][1]);
            p.d[3] = pk2(sacc[2*kk+1][qt][2], sacc[2*kk+1][qt][3]);
            #pragma unroll
            for (int ntl = 0; ntl < 2; ++ntl)
                oT[ntl][qt] = __builtin_amdgcn_mfma_f32_16x16x32_bf16(vfr[ntl], p.v, oT[ntl][qt], 0, 0, 0);
        }
    }

    // attn_out -> bufO [64][AO_STR], b64 stores
    #pragma unroll
    for (int qt = 0; qt < 4; ++qt)
        #pragma unroll
        for (int ntl = 0; ntl < 2; ++ntl) {
            v2u o;
            o.x = pk2(oT[ntl][qt][0], oT[ntl][qt][1]);
            o.y = pk2(oT[ntl][qt][2], oT[ntl][qt][3]);
            *(v2u*)&bufO[(qt*16 + l15)*AO_STR + wv*32 + ntl*16 + 4*g] = o;
        }
    __syncthreads();   // B2: AO complete

    // ---------- phase 3: transposed proj GEMM + direct register scatter (r5-proven) ----------
    v4f pacc[2][4];    // [ntl][qt]: P[out=wv*32+16ntl+4g+r][tok=16qt+l15]
    #pragma unroll
    for (int ntl = 0; ntl < 2; ++ntl)
        #pragma unroll
        for (int qt = 0; qt < 4; ++qt)
            pacc[ntl][qt] = (v4f){0.f,0.f,0.f,0.f};
    #pragma unroll
    for (int kk = 0; kk < 6; ++kk) {
        v8s aofr[4];
        #pragma unroll
        for (int qt = 0; qt < 4; ++qt)
            aofr[qt] = *(const v8s*)&bufO[(qt*16 + l15)*AO_STR + kk*32 + g*8];
        #pragma unroll
        for (int ntl = 0; ntl < 2; ++ntl) {
            v8s pwfr = *(const v8s*)(pw + (size_t)(wv*32 + ntl*16 + l15)*DIM + kk*32 + g*8);
            #pragma unroll
            for (int qt = 0; qt < 4; ++qt)
                pacc[ntl][qt] = __builtin_amdgcn_mfma_f32_16x16x32_bf16(pwfr, aofr[qt], pacc[ntl][qt], 0, 0, 0);
        }
    }
    float pb[2][4];
    #pragma unroll
    for (int ntl = 0; ntl < 2; ++ntl) {
        v4f pbv = *(const v4f*)&proj_b[wv*32 + ntl*16 + 4*g];
        #pragma unroll
        for (int r = 0; r < 4; ++r) pb[ntl][r] = pbv[r];
    }

    float* ob = out + (size_t)b * DIM*IMG*IMG;
    #pragma unroll
    for (int qt = 0; qt < 4; ++qt) {
        const int strow = 2*qt + (l15 >> 3);
        const int stcol = l15 & 7;
        int hh = wi*8 + strow + 4; if (hh >= IMG) hh -= IMG;
        int ww = wj*8 + stcol + 4; if (ww >= IMG) ww -= IMG;
        const size_t pix = (size_t)hh*IMG + ww;
        #pragma unroll
        for (int ntl = 0; ntl < 2; ++ntl)
            #pragma unroll
            for (int r = 0; r < 4; ++r) {
                const int c = wv*32 + ntl*16 + 4*g + r;
                ob[(size_t)c*(IMG*IMG) + pix] = pacc[ntl][qt][r] + pb[ntl][r];
            }
    }
}

extern "C" void kernel_launch(void* const* d_in, const int* in_sizes, int n_in,
                              void* d_out, int out_size, void* d_ws, size_t ws_size,
                              hipStream_t stream) {
    const float* x        = (const float*)d_in[0];
    const float* qkv_w    = (const float*)d_in[1];
    const float* qkv_b    = (const float*)d_in[2];
    const float* proj_w   = (const float*)d_in[3];
    const float* proj_b   = (const float*)d_in[4];
    const float* rel_bias = (const float*)d_in[5];
    const int*   rel_idx  = (const int*)d_in[6];

    u16*   qw_bf  = (u16*)d_ws;                         // 221184 B
    u16*   pw_bf  = (u16*)((char*)d_ws + 221184);       //  73728 B
    float* qb2    = (float*)((char*)d_ws + 294912);     //   2304 B
    float* biasT  = (float*)((char*)d_ws + 297216);     //  98304 B
    float* out    = (float*)d_out;

    hipLaunchKernelGGL(prep_kernel, dim3(432), dim3(256), 0, stream,
                       qkv_w, qkv_b, proj_w, rel_bias, rel_idx, qw_bf, pw_bf, qb2, biasT);
    hipLaunchKernelGGL(winattn_kernel, dim3(NWINDOWS), dim3(384), 0, stream,
                       x, proj_b, qw_bf, pw_bf, qb2, biasT, out);
}